// Round 1
// baseline (628.571 us; speedup 1.0000x reference)
//
#include <hip/hip_runtime.h>
#include <hip/hip_bf16.h>

#define NTOK 8192
#define DMODEL 1024
#define NEXP 8
#define HID 2752
#define ALPHA 0.05f

#define BM 128
#define BN 128
#define BK 64
#define MAXTILES 72

typedef __attribute__((ext_vector_type(8))) short bf16x8;
typedef __attribute__((ext_vector_type(8))) unsigned short u16x8;
typedef __attribute__((ext_vector_type(4))) float f32x4;

__device__ __forceinline__ unsigned short f2bf(float f){
  unsigned u = __builtin_bit_cast(unsigned, f);
  u += 0x7fffu + ((u >> 16) & 1u);   // RNE
  return (unsigned short)(u >> 16);
}

// ---------------- init ----------------
__global__ void k_init(int* counts, int* cursor, float* ce_sum){
  int t = threadIdx.x;
  if (t < NEXP){ counts[t] = 0; cursor[t] = 0; ce_sum[t] = 0.f; }
}

// ---------------- router: logits, softmax, top1, gate, counts, ce ----------------
__global__ __launch_bounds__(1024) void k_router(
    const float* __restrict__ x, const float* __restrict__ Wg,
    const float* __restrict__ bg, int* __restrict__ counts,
    float* __restrict__ ce_sum, int* __restrict__ top1, float* __restrict__ gate)
{
  __shared__ float wg[NEXP*DMODEL];   // 32 KiB
  __shared__ float ce_blk[NEXP];
  __shared__ int   cnt_blk[NEXP];
  const int tid = threadIdx.x;
  for (int i = tid; i < NEXP*DMODEL; i += 1024) wg[i] = Wg[i];
  if (tid < NEXP){ ce_blk[tid] = 0.f; cnt_blk[tid] = 0; }
  __syncthreads();
  const int wave = tid >> 6, lane = tid & 63;
  const int t = blockIdx.x * 16 + wave;     // 16 tokens/block, grid=512
  float acc[NEXP];
  #pragma unroll
  for (int e = 0; e < NEXP; e++) acc[e] = 0.f;
  const float* xr = x + (size_t)t * DMODEL;
  #pragma unroll
  for (int kb = 0; kb < DMODEL; kb += 256){
    const float4 xv = *(const float4*)(xr + kb + lane*4);
    #pragma unroll
    for (int e = 0; e < NEXP; e++){
      const float4 wv = *(const float4*)(wg + e*DMODEL + kb + lane*4);
      acc[e] += xv.x*wv.x + xv.y*wv.y + xv.z*wv.z + xv.w*wv.w;
    }
  }
  #pragma unroll
  for (int e = 0; e < NEXP; e++){
    float v = acc[e];
    #pragma unroll
    for (int off = 32; off; off >>= 1) v += __shfl_xor(v, off);
    acc[e] = v;
  }
  if (lane == 0){
    float mx = -1e30f; int bi = 0;
    float lg[NEXP];
    #pragma unroll
    for (int e = 0; e < NEXP; e++){
      lg[e] = acc[e] + bg[e];
      if (lg[e] > mx){ mx = lg[e]; bi = e; }   // first max -> matches jnp.argmax
    }
    float s = 0.f, p[NEXP];
    #pragma unroll
    for (int e = 0; e < NEXP; e++){ p[e] = __expf(lg[e]-mx); s += p[e]; }
    const float inv = 1.f/s;
    #pragma unroll
    for (int e = 0; e < NEXP; e++) atomicAdd(&ce_blk[e], p[e]*inv);
    top1[t] = bi;
    gate[t] = p[bi]*inv;
    atomicAdd(&cnt_blk[bi], 1);
  }
  __syncthreads();
  if (tid < NEXP){
    atomicAdd(&counts[tid], cnt_blk[tid]);
    atomicAdd(&ce_sum[tid], ce_blk[tid]);
  }
}

// ---------------- x -> bf16 ----------------
__global__ __launch_bounds__(256) void k_cvt(const float* __restrict__ x,
                                             unsigned short* __restrict__ xb)
{
  const size_t i = (size_t)blockIdx.x*256 + threadIdx.x; // 8 floats each
  const float4* src = (const float4*)x + i*2;
  const float4 a = src[0], b = src[1];
  u16x8 o;
  o[0]=f2bf(a.x); o[1]=f2bf(a.y); o[2]=f2bf(a.z); o[3]=f2bf(a.w);
  o[4]=f2bf(b.x); o[5]=f2bf(b.y); o[6]=f2bf(b.z); o[7]=f2bf(b.w);
  ((u16x8*)xb)[i] = o;
}

// ---------------- scan: offsets, tile table, aux ----------------
__global__ void k_scan(const int* __restrict__ counts, const float* __restrict__ ce_sum,
                       int* offsets, int* nTiles, int* tileE, int* tileBase, int* tileCnt,
                       float* aux_out)
{
  if (threadIdx.x == 0){
    int off = 0;
    for (int e = 0; e < NEXP; e++){ offsets[e] = off; off += counts[e]; }
    offsets[NEXP] = off;
    int nt = 0;
    for (int e = 0; e < NEXP; e++){
      for (int r = 0; r < counts[e]; r += BM){
        tileE[nt] = e;
        tileBase[nt] = offsets[e] + r;
        int rem = counts[e] - r;
        tileCnt[nt] = rem < BM ? rem : BM;
        nt++;
      }
    }
    *nTiles = nt;
    float aux = 0.f;
    for (int e = 0; e < NEXP; e++)
      aux += ((float)counts[e] / (float)NTOK) * (ce_sum[e] / (float)NTOK);
    aux_out[0] = ALPHA * (float)NEXP * aux;
  }
}

// ---------------- scatter: perm[slot] = token (wave-aggregated atomics) ----------------
__global__ __launch_bounds__(256) void k_scatter(const int* __restrict__ top1,
                                                 int* cursor, const int* __restrict__ offsets,
                                                 int* __restrict__ perm)
{
  const int t = blockIdx.x*256 + threadIdx.x;
  const int e = top1[t];
  const int lane = threadIdx.x & 63;
  int slot = 0;
  #pragma unroll
  for (int ee = 0; ee < NEXP; ee++){
    unsigned long long mask = __ballot(e == ee);
    if (e == ee){
      int leader = __ffsll(mask) - 1;
      int nbelow = __popcll(mask & ((1ull << lane) - 1ull));
      int base = 0;
      if (lane == leader) base = atomicAdd(&cursor[ee], __popcll(mask));
      base = __shfl(base, leader);
      slot = offsets[ee] + base + nbelow;
    }
  }
  perm[slot] = t;
}

// ---------------- up: h = silu(x@Wu^T) * (x@Wv^T), grouped 128x128, bf16 MFMA ----------------
__global__ __launch_bounds__(256,2) void k_up(
    const unsigned short* __restrict__ xb,
    const float* __restrict__ Wu, const float* __restrict__ Wv,
    const int* __restrict__ perm,
    const int* __restrict__ nTiles, const int* __restrict__ tileE,
    const int* __restrict__ tileBase, const int* __restrict__ tileCnt,
    unsigned short* __restrict__ h)
{
  if ((int)blockIdx.x >= *nTiles) return;
  const int e    = tileE[blockIdx.x];
  const int base = tileBase[blockIdx.x];
  const int cnt  = tileCnt[blockIdx.x];
  const int ncol0 = blockIdx.y * BN;

  __shared__ __align__(16) unsigned short As [BM*BK]; // 16KB each, XOR-swizzled rows
  __shared__ __align__(16) unsigned short Bus[BN*BK];
  __shared__ __align__(16) unsigned short Bvs[BN*BK];

  const int tid  = threadIdx.x;
  const int srow = tid >> 1;
  const int sseg = tid & 1;

  const int arow = (srow < cnt) ? srow : 0;
  const int tokA = perm[base + arow];
  const unsigned short* aSrc = xb + (size_t)tokA * DMODEL + sseg*32;
  int brow = ncol0 + srow; if (brow >= HID) brow = HID - 1;
  const float* buSrc = Wu + ((size_t)e*HID + brow)*DMODEL + sseg*32;
  const float* bvSrc = Wv + ((size_t)e*HID + brow)*DMODEL + sseg*32;

  char* aBase  = (char*)As  + srow*128;
  char* buBase = (char*)Bus + srow*128;
  char* bvBase = (char*)Bvs + srow*128;
  const int swz = (srow & 7) << 4;

  const int wid = tid >> 6, lane = tid & 63;
  const int wm = (wid >> 1) * 64, wn = (wid & 1) * 64;
  const int fr = lane & 15, fq = lane >> 4;

  f32x4 accU[4][4], accV[4][4];
  #pragma unroll
  for (int m = 0; m < 4; m++)
    #pragma unroll
    for (int n = 0; n < 4; n++)
      #pragma unroll
      for (int j = 0; j < 4; j++){ accU[m][n][j] = 0.f; accV[m][n][j] = 0.f; }

  for (int kb = 0; kb < DMODEL; kb += BK){
    #pragma unroll
    for (int c = 0; c < 4; c++){
      u16x8 av = *(const u16x8*)(aSrc + kb + c*8);
      *(u16x8*)(aBase + ((sseg*64 + c*16) ^ swz)) = av;
    }
    #pragma unroll
    for (int c = 0; c < 4; c++){
      float4 f0 = *(const float4*)(buSrc + kb + c*8);
      float4 f1 = *(const float4*)(buSrc + kb + c*8 + 4);
      u16x8 o;
      o[0]=f2bf(f0.x); o[1]=f2bf(f0.y); o[2]=f2bf(f0.z); o[3]=f2bf(f0.w);
      o[4]=f2bf(f1.x); o[5]=f2bf(f1.y); o[6]=f2bf(f1.z); o[7]=f2bf(f1.w);
      *(u16x8*)(buBase + ((sseg*64 + c*16) ^ swz)) = o;
    }
    #pragma unroll
    for (int c = 0; c < 4; c++){
      float4 f0 = *(const float4*)(bvSrc + kb + c*8);
      float4 f1 = *(const float4*)(bvSrc + kb + c*8 + 4);
      u16x8 o;
      o[0]=f2bf(f0.x); o[1]=f2bf(f0.y); o[2]=f2bf(f0.z); o[3]=f2bf(f0.w);
      o[4]=f2bf(f1.x); o[5]=f2bf(f1.y); o[6]=f2bf(f1.z); o[7]=f2bf(f1.w);
      *(u16x8*)(bvBase + ((sseg*64 + c*16) ^ swz)) = o;
    }
    __syncthreads();
    #pragma unroll
    for (int ks = 0; ks < 2; ks++){
      bf16x8 af[4], bu[4], bv[4];
      #pragma unroll
      for (int m = 0; m < 4; m++){
        int r = wm + m*16 + fr;
        af[m] = *(const bf16x8*)((const char*)As + r*128 + ((ks*64 + fq*16) ^ ((r&7)<<4)));
      }
      #pragma unroll
      for (int n = 0; n < 4; n++){
        int r = wn + n*16 + fr;
        bu[n] = *(const bf16x8*)((const char*)Bus + r*128 + ((ks*64 + fq*16) ^ ((r&7)<<4)));
        bv[n] = *(const bf16x8*)((const char*)Bvs + r*128 + ((ks*64 + fq*16) ^ ((r&7)<<4)));
      }
      #pragma unroll
      for (int m = 0; m < 4; m++)
        #pragma unroll
        for (int n = 0; n < 4; n++){
          accU[m][n] = __builtin_amdgcn_mfma_f32_16x16x32_bf16(af[m], bu[n], accU[m][n], 0,0,0);
          accV[m][n] = __builtin_amdgcn_mfma_f32_16x16x32_bf16(af[m], bv[n], accV[m][n], 0,0,0);
        }
    }
    __syncthreads();
  }
  // epilogue: silu(u)*v -> h (bf16)
  #pragma unroll
  for (int m = 0; m < 4; m++)
    #pragma unroll
    for (int n = 0; n < 4; n++)
      #pragma unroll
      for (int j = 0; j < 4; j++){
        int r = wm + m*16 + fq*4 + j;
        int c = ncol0 + wn + n*16 + fr;
        if (r < cnt && c < HID){
          float u = accU[m][n][j], v = accV[m][n][j];
          float hv = (u / (1.f + __expf(-u))) * v;
          h[(size_t)(base + r)*HID + c] = f2bf(hv);
        }
      }
}

// ---------------- down: y[tok] = gate * (h_slot @ Wd[e]^T), grouped 128x128 ----------------
__global__ __launch_bounds__(256,2) void k_down(
    const unsigned short* __restrict__ h, const float* __restrict__ Wd,
    const int* __restrict__ perm, const float* __restrict__ gate,
    const int* __restrict__ nTiles, const int* __restrict__ tileE,
    const int* __restrict__ tileBase, const int* __restrict__ tileCnt,
    float* __restrict__ out)
{
  if ((int)blockIdx.x >= *nTiles) return;
  const int e    = tileE[blockIdx.x];
  const int base = tileBase[blockIdx.x];
  const int cnt  = tileCnt[blockIdx.x];
  const int ncol0 = blockIdx.y * BN;   // D cols

  __shared__ __align__(16) unsigned short As[BM*BK];
  __shared__ __align__(16) unsigned short Bs[BM*BK];
  __shared__ int   tokL[BM];
  __shared__ float gateL[BM];

  const int tid = threadIdx.x;
  if (tid < BM){
    int rr = (tid < cnt) ? tid : 0;
    int tk = perm[base + rr];
    tokL[tid] = tk;
    gateL[tid] = gate[tk];
  }
  const int srow = tid >> 1;
  const int sseg = tid & 1;
  const int aslot = base + ((srow < cnt) ? srow : 0);
  const unsigned short* aSrc = h + (size_t)aslot*HID + sseg*32;
  const float* bSrc = Wd + ((size_t)e*DMODEL + ncol0 + srow)*HID + sseg*32;

  char* aBase = (char*)As + srow*128;
  char* bBase = (char*)Bs + srow*128;
  const int swz = (srow & 7) << 4;

  const int wid = tid >> 6, lane = tid & 63;
  const int wm = (wid >> 1) * 64, wn = (wid & 1) * 64;
  const int fr = lane & 15, fq = lane >> 4;

  f32x4 acc[4][4];
  #pragma unroll
  for (int m = 0; m < 4; m++)
    #pragma unroll
    for (int n = 0; n < 4; n++)
      #pragma unroll
      for (int j = 0; j < 4; j++) acc[m][n][j] = 0.f;

  for (int kb = 0; kb < HID; kb += BK){   // 43 iters exactly
    #pragma unroll
    for (int c = 0; c < 4; c++){
      u16x8 av = *(const u16x8*)(aSrc + kb + c*8);
      *(u16x8*)(aBase + ((sseg*64 + c*16) ^ swz)) = av;
    }
    #pragma unroll
    for (int c = 0; c < 4; c++){
      float4 f0 = *(const float4*)(bSrc + kb + c*8);
      float4 f1 = *(const float4*)(bSrc + kb + c*8 + 4);
      u16x8 o;
      o[0]=f2bf(f0.x); o[1]=f2bf(f0.y); o[2]=f2bf(f0.z); o[3]=f2bf(f0.w);
      o[4]=f2bf(f1.x); o[5]=f2bf(f1.y); o[6]=f2bf(f1.z); o[7]=f2bf(f1.w);
      *(u16x8*)(bBase + ((sseg*64 + c*16) ^ swz)) = o;
    }
    __syncthreads();
    #pragma unroll
    for (int ks = 0; ks < 2; ks++){
      bf16x8 af[4], bf[4];
      #pragma unroll
      for (int m = 0; m < 4; m++){
        int r = wm + m*16 + fr;
        af[m] = *(const bf16x8*)((const char*)As + r*128 + ((ks*64 + fq*16) ^ ((r&7)<<4)));
      }
      #pragma unroll
      for (int n = 0; n < 4; n++){
        int r = wn + n*16 + fr;
        bf[n] = *(const bf16x8*)((const char*)Bs + r*128 + ((ks*64 + fq*16) ^ ((r&7)<<4)));
      }
      #pragma unroll
      for (int m = 0; m < 4; m++)
        #pragma unroll
        for (int n = 0; n < 4; n++)
          acc[m][n] = __builtin_amdgcn_mfma_f32_16x16x32_bf16(af[m], bf[n], acc[m][n], 0,0,0);
    }
    __syncthreads();
  }
  #pragma unroll
  for (int m = 0; m < 4; m++)
    #pragma unroll
    for (int n = 0; n < 4; n++)
      #pragma unroll
      for (int j = 0; j < 4; j++){
        int r = wm + m*16 + fq*4 + j;
        int c = ncol0 + wn + n*16 + fr;
        if (r < cnt)
          out[(size_t)tokL[r]*DMODEL + c] = acc[m][n][j] * gateL[r];
      }
}

// ---------------- launch ----------------
extern "C" void kernel_launch(void* const* d_in, const int* in_sizes, int n_in,
                              void* d_out, int out_size, void* d_ws, size_t ws_size,
                              hipStream_t stream)
{
  const float* x  = (const float*)d_in[0];
  const float* Wg = (const float*)d_in[1];
  const float* bg = (const float*)d_in[2];
  const float* Wu = (const float*)d_in[3];
  const float* Wv = (const float*)d_in[4];
  const float* Wd = (const float*)d_in[5];
  float* out = (float*)d_out;

  char* ws = (char*)d_ws;
  int*   counts   = (int*)(ws + 0);
  int*   cursor   = (int*)(ws + 32);
  int*   offsets  = (int*)(ws + 64);
  float* ce_sum   = (float*)(ws + 128);
  int*   nTiles   = (int*)(ws + 192);
  int*   tileE    = (int*)(ws + 256);
  int*   tileBase = (int*)(ws + 768);
  int*   tileCnt  = (int*)(ws + 1280);
  int*   top1     = (int*)(ws + 2048);
  float* gate     = (float*)(ws + 34816);
  int*   perm     = (int*)(ws + 67584);
  unsigned short* xb   = (unsigned short*)(ws + 100352);
  unsigned short* hbuf = (unsigned short*)(ws + 100352 + (size_t)NTOK*DMODEL*2);
  // total ws usage: ~59.1 MB

  k_init<<<1, 64, 0, stream>>>(counts, cursor, ce_sum);
  k_router<<<NTOK/16, 1024, 0, stream>>>(x, Wg, bg, counts, ce_sum, top1, gate);
  k_cvt<<<(NTOK*DMODEL/8)/256, 256, 0, stream>>>(x, xb);
  k_scan<<<1, 64, 0, stream>>>(counts, ce_sum, offsets, nTiles, tileE, tileBase, tileCnt,
                               out + (size_t)NTOK*DMODEL);
  k_scatter<<<NTOK/256, 256, 0, stream>>>(top1, cursor, offsets, perm);
  dim3 gUp(MAXTILES, (HID + BN - 1)/BN);   // 72 x 22
  k_up<<<gUp, 256, 0, stream>>>(xb, Wu, Wv, perm, nTiles, tileE, tileBase, tileCnt, hbuf);
  dim3 gDn(MAXTILES, DMODEL/BN);           // 72 x 8
  k_down<<<gDn, 256, 0, stream>>>(hbuf, Wd, perm, gate, nTiles, tileE, tileBase, tileCnt, out);
}

// Round 2
// 363.879 us; speedup vs baseline: 1.7274x; 1.7274x over previous
//
#include <hip/hip_runtime.h>
#include <hip/hip_bf16.h>

#define NTOK 8192
#define DMODEL 1024
#define NEXP 8
#define HID 2752
#define ALPHA 0.05f

#define BM 128
#define BN 128
#define BK 64
#define MAXTILES 72

typedef __attribute__((ext_vector_type(8))) short bf16x8;
typedef __attribute__((ext_vector_type(8))) unsigned short u16x8;
typedef __attribute__((ext_vector_type(4))) float f32x4;

__device__ __forceinline__ unsigned short f2bf(float f){
  unsigned u = __builtin_bit_cast(unsigned, f);
  u += 0x7fffu + ((u >> 16) & 1u);   // RNE
  return (unsigned short)(u >> 16);
}

__device__ __forceinline__ void gload16(const void* g, void* l){
  __builtin_amdgcn_global_load_lds(
      (const __attribute__((address_space(1))) unsigned int*)g,
      (__attribute__((address_space(3))) unsigned int*)l, 16, 0, 0);
}

// ---------------- init ----------------
__global__ void k_init(int* counts, int* cursor, float* ce_sum){
  int t = threadIdx.x;
  if (t < NEXP){ counts[t] = 0; cursor[t] = 0; ce_sum[t] = 0.f; }
}

// ---------------- router ----------------
__global__ __launch_bounds__(1024) void k_router(
    const float* __restrict__ x, const float* __restrict__ Wg,
    const float* __restrict__ bg, int* __restrict__ counts,
    float* __restrict__ ce_sum, int* __restrict__ top1, float* __restrict__ gate)
{
  __shared__ float wg[NEXP*DMODEL];
  __shared__ float ce_blk[NEXP];
  __shared__ int   cnt_blk[NEXP];
  const int tid = threadIdx.x;
  for (int i = tid; i < NEXP*DMODEL; i += 1024) wg[i] = Wg[i];
  if (tid < NEXP){ ce_blk[tid] = 0.f; cnt_blk[tid] = 0; }
  __syncthreads();
  const int wave = tid >> 6, lane = tid & 63;
  const int t = blockIdx.x * 16 + wave;
  float acc[NEXP];
  #pragma unroll
  for (int e = 0; e < NEXP; e++) acc[e] = 0.f;
  const float* xr = x + (size_t)t * DMODEL;
  #pragma unroll
  for (int kb = 0; kb < DMODEL; kb += 256){
    const float4 xv = *(const float4*)(xr + kb + lane*4);
    #pragma unroll
    for (int e = 0; e < NEXP; e++){
      const float4 wv = *(const float4*)(wg + e*DMODEL + kb + lane*4);
      acc[e] += xv.x*wv.x + xv.y*wv.y + xv.z*wv.z + xv.w*wv.w;
    }
  }
  #pragma unroll
  for (int e = 0; e < NEXP; e++){
    float v = acc[e];
    #pragma unroll
    for (int off = 32; off; off >>= 1) v += __shfl_xor(v, off);
    acc[e] = v;
  }
  if (lane == 0){
    float mx = -1e30f; int bi = 0;
    float lg[NEXP];
    #pragma unroll
    for (int e = 0; e < NEXP; e++){
      lg[e] = acc[e] + bg[e];
      if (lg[e] > mx){ mx = lg[e]; bi = e; }
    }
    float s = 0.f, p[NEXP];
    #pragma unroll
    for (int e = 0; e < NEXP; e++){ p[e] = __expf(lg[e]-mx); s += p[e]; }
    const float inv = 1.f/s;
    #pragma unroll
    for (int e = 0; e < NEXP; e++) atomicAdd(&ce_blk[e], p[e]*inv);
    top1[t] = bi;
    gate[t] = p[bi]*inv;
    atomicAdd(&cnt_blk[bi], 1);
  }
  __syncthreads();
  if (tid < NEXP){
    atomicAdd(&counts[tid], cnt_blk[tid]);
    atomicAdd(&ce_sum[tid], ce_blk[tid]);
  }
}

// ---------------- f32 -> bf16 (grid-stride, vec8) ----------------
__global__ __launch_bounds__(256) void k_cvtn(const float* __restrict__ s,
                                              unsigned short* __restrict__ d, int n8)
{
  for (size_t i = (size_t)blockIdx.x*256 + threadIdx.x; i < (size_t)n8; i += (size_t)2048*256){
    const float4 a = ((const float4*)s)[i*2];
    const float4 b = ((const float4*)s)[i*2+1];
    u16x8 o;
    o[0]=f2bf(a.x); o[1]=f2bf(a.y); o[2]=f2bf(a.z); o[3]=f2bf(a.w);
    o[4]=f2bf(b.x); o[5]=f2bf(b.y); o[6]=f2bf(b.z); o[7]=f2bf(b.w);
    ((u16x8*)d)[i] = o;
  }
}

// ---------------- scan ----------------
__global__ void k_scan(const int* __restrict__ counts, const float* __restrict__ ce_sum,
                       int* offsets, int* nTiles, int* tileE, int* tileBase, int* tileCnt,
                       float* aux_out)
{
  if (threadIdx.x == 0){
    int off = 0;
    for (int e = 0; e < NEXP; e++){ offsets[e] = off; off += counts[e]; }
    offsets[NEXP] = off;
    int nt = 0;
    for (int e = 0; e < NEXP; e++){
      for (int r = 0; r < counts[e]; r += BM){
        tileE[nt] = e;
        tileBase[nt] = offsets[e] + r;
        int rem = counts[e] - r;
        tileCnt[nt] = rem < BM ? rem : BM;
        nt++;
      }
    }
    *nTiles = nt;
    float aux = 0.f;
    for (int e = 0; e < NEXP; e++)
      aux += ((float)counts[e] / (float)NTOK) * (ce_sum[e] / (float)NTOK);
    aux_out[0] = ALPHA * (float)NEXP * aux;
  }
}

// ---------------- scatter ----------------
__global__ __launch_bounds__(256) void k_scatter(const int* __restrict__ top1,
                                                 int* cursor, const int* __restrict__ offsets,
                                                 int* __restrict__ perm)
{
  const int t = blockIdx.x*256 + threadIdx.x;
  const int e = top1[t];
  const int lane = threadIdx.x & 63;
  int slot = 0;
  #pragma unroll
  for (int ee = 0; ee < NEXP; ee++){
    unsigned long long mask = __ballot(e == ee);
    if (e == ee){
      int leader = __ffsll(mask) - 1;
      int nbelow = __popcll(mask & ((1ull << lane) - 1ull));
      int base = 0;
      if (lane == leader) base = atomicAdd(&cursor[ee], __popcll(mask));
      base = __shfl(base, leader);
      slot = offsets[ee] + base + nbelow;
    }
  }
  perm[slot] = t;
}

// ============ bf16-weight path: m97-style gload_lds GEMMs ============
// LDS linear dest + inverse-swizzled per-lane global source + swizzled ds_read.
// Swizzle: 16B-seg ^= (row&7), row = 128B (BK=64 bf16).

__global__ __launch_bounds__(256,2) void k_up16(
    const unsigned short* __restrict__ xb,
    const unsigned short* __restrict__ Wub, const unsigned short* __restrict__ Wvb,
    const int* __restrict__ perm,
    const int* __restrict__ nTiles, const int* __restrict__ tileE,
    const int* __restrict__ tileBase, const int* __restrict__ tileCnt,
    unsigned short* __restrict__ h)
{
  if ((int)blockIdx.x >= *nTiles) return;
  const int e    = tileE[blockIdx.x];
  const int base = tileBase[blockIdx.x];
  const int cnt  = tileCnt[blockIdx.x];
  const int ncol0 = blockIdx.y * BN;

  __shared__ __align__(16) unsigned short As [BM*BK];
  __shared__ __align__(16) unsigned short Bus[BN*BK];
  __shared__ __align__(16) unsigned short Bvs[BN*BK];

  const int tid = threadIdx.x;
  const int wv = tid >> 6, ln = tid & 63;

  // per-lane pre-swizzled sources; 4 chunks of 8 rows per wave
  const unsigned short* srcA[4];
  const unsigned short* srcU[4];
  const unsigned short* srcV[4];
  #pragma unroll
  for (int c = 0; c < 4; c++){
    const int r  = wv*32 + c*8 + (ln>>3);      // LDS row 0..127
    const int sp = (ln&7) ^ (r&7);             // inverse-swizzled 16B segment
    const int ra = (r < cnt) ? r : (cnt-1);
    srcA[c] = xb + (size_t)perm[base + ra]*DMODEL + sp*8;
    int rb = ncol0 + r; if (rb >= HID) rb = HID-1;   // clamped rows are masked at write
    srcU[c] = Wub + ((size_t)e*HID + rb)*DMODEL + sp*8;
    srcV[c] = Wvb + ((size_t)e*HID + rb)*DMODEL + sp*8;
  }

  const int wm = (wv >> 1) * 64, wn = (wv & 1) * 64;
  const int fr = ln & 15, fq = ln >> 4;

  f32x4 accU[4][4], accV[4][4];
  #pragma unroll
  for (int m = 0; m < 4; m++)
    #pragma unroll
    for (int n = 0; n < 4; n++)
      #pragma unroll
      for (int j = 0; j < 4; j++){ accU[m][n][j] = 0.f; accV[m][n][j] = 0.f; }

  for (int kb = 0; kb < DMODEL; kb += BK){
    #pragma unroll
    for (int c = 0; c < 4; c++){
      const unsigned ldo = wv*4096 + c*1024;   // wave-uniform LDS byte offset
      gload16(srcA[c] + kb, (char*)As  + ldo);
      gload16(srcU[c] + kb, (char*)Bus + ldo);
      gload16(srcV[c] + kb, (char*)Bvs + ldo);
    }
    __syncthreads();
    #pragma unroll
    for (int ks = 0; ks < 2; ks++){
      bf16x8 af[4], bu[4], bv[4];
      #pragma unroll
      for (int m = 0; m < 4; m++){
        int r = wm + m*16 + fr;
        af[m] = *(const bf16x8*)((const char*)As + r*128 + ((ks*64 + fq*16) ^ ((r&7)<<4)));
      }
      #pragma unroll
      for (int n = 0; n < 4; n++){
        int r = wn + n*16 + fr;
        bu[n] = *(const bf16x8*)((const char*)Bus + r*128 + ((ks*64 + fq*16) ^ ((r&7)<<4)));
        bv[n] = *(const bf16x8*)((const char*)Bvs + r*128 + ((ks*64 + fq*16) ^ ((r&7)<<4)));
      }
      #pragma unroll
      for (int m = 0; m < 4; m++)
        #pragma unroll
        for (int n = 0; n < 4; n++){
          accU[m][n] = __builtin_amdgcn_mfma_f32_16x16x32_bf16(af[m], bu[n], accU[m][n], 0,0,0);
          accV[m][n] = __builtin_amdgcn_mfma_f32_16x16x32_bf16(af[m], bv[n], accV[m][n], 0,0,0);
        }
    }
    __syncthreads();
  }
  #pragma unroll
  for (int m = 0; m < 4; m++)
    #pragma unroll
    for (int n = 0; n < 4; n++)
      #pragma unroll
      for (int j = 0; j < 4; j++){
        int r = wm + m*16 + fq*4 + j;
        int c = ncol0 + wn + n*16 + fr;
        if (r < cnt && c < HID){
          float u = accU[m][n][j], v = accV[m][n][j];
          float hv = (u / (1.f + __expf(-u))) * v;
          h[(size_t)(base + r)*HID + c] = f2bf(hv);
        }
      }
}

__global__ __launch_bounds__(256,2) void k_down16(
    const unsigned short* __restrict__ h, const unsigned short* __restrict__ Wdb,
    const int* __restrict__ perm, const float* __restrict__ gate,
    const int* __restrict__ nTiles, const int* __restrict__ tileE,
    const int* __restrict__ tileBase, const int* __restrict__ tileCnt,
    float* __restrict__ out)
{
  if ((int)blockIdx.x >= *nTiles) return;
  const int e    = tileE[blockIdx.x];
  const int base = tileBase[blockIdx.x];
  const int cnt  = tileCnt[blockIdx.x];
  const int ncol0 = blockIdx.y * BN;

  __shared__ __align__(16) unsigned short As[BM*BK];
  __shared__ __align__(16) unsigned short Bs[BM*BK];
  __shared__ int   tokL[BM];
  __shared__ float gateL[BM];

  const int tid = threadIdx.x;
  if (tid < BM){
    int rr = (tid < cnt) ? tid : 0;
    int tk = perm[base + rr];
    tokL[tid] = tk;
    gateL[tid] = gate[tk];
  }
  const int wv = tid >> 6, ln = tid & 63;

  const unsigned short* srcA[4];
  const unsigned short* srcB[4];
  #pragma unroll
  for (int c = 0; c < 4; c++){
    const int r  = wv*32 + c*8 + (ln>>3);
    const int sp = (ln&7) ^ (r&7);
    const int ra = (r < cnt) ? r : (cnt-1);
    srcA[c] = h + (size_t)(base + ra)*HID + sp*8;
    const int rb = ncol0 + r;                     // < 1024 always
    srcB[c] = Wdb + ((size_t)e*DMODEL + rb)*HID + sp*8;
  }

  const int wm = (wv >> 1) * 64, wn = (wv & 1) * 64;
  const int fr = ln & 15, fq = ln >> 4;

  f32x4 acc[4][4];
  #pragma unroll
  for (int m = 0; m < 4; m++)
    #pragma unroll
    for (int n = 0; n < 4; n++)
      #pragma unroll
      for (int j = 0; j < 4; j++) acc[m][n][j] = 0.f;

  for (int kb = 0; kb < HID; kb += BK){   // 43 iters
    #pragma unroll
    for (int c = 0; c < 4; c++){
      const unsigned ldo = wv*4096 + c*1024;
      gload16(srcA[c] + kb, (char*)As + ldo);
      gload16(srcB[c] + kb, (char*)Bs + ldo);
    }
    __syncthreads();
    #pragma unroll
    for (int ks = 0; ks < 2; ks++){
      bf16x8 af[4], bf[4];
      #pragma unroll
      for (int m = 0; m < 4; m++){
        int r = wm + m*16 + fr;
        af[m] = *(const bf16x8*)((const char*)As + r*128 + ((ks*64 + fq*16) ^ ((r&7)<<4)));
      }
      #pragma unroll
      for (int n = 0; n < 4; n++){
        int r = wn + n*16 + fr;
        bf[n] = *(const bf16x8*)((const char*)Bs + r*128 + ((ks*64 + fq*16) ^ ((r&7)<<4)));
      }
      #pragma unroll
      for (int m = 0; m < 4; m++)
        #pragma unroll
        for (int n = 0; n < 4; n++)
          acc[m][n] = __builtin_amdgcn_mfma_f32_16x16x32_bf16(af[m], bf[n], acc[m][n], 0,0,0);
    }
    __syncthreads();
  }
  #pragma unroll
  for (int m = 0; m < 4; m++)
    #pragma unroll
    for (int n = 0; n < 4; n++)
      #pragma unroll
      for (int j = 0; j < 4; j++){
        int r = wm + m*16 + fq*4 + j;
        int c = ncol0 + wn + n*16 + fr;
        if (r < cnt)
          out[(size_t)tokL[r]*DMODEL + c] = acc[m][n][j] * gateL[r];
      }
}

// ============ f32-weight fallback (verified round-1 kernels) ============
__global__ __launch_bounds__(256,2) void k_upf(
    const unsigned short* __restrict__ xb,
    const float* __restrict__ Wu, const float* __restrict__ Wv,
    const int* __restrict__ perm,
    const int* __restrict__ nTiles, const int* __restrict__ tileE,
    const int* __restrict__ tileBase, const int* __restrict__ tileCnt,
    unsigned short* __restrict__ h)
{
  if ((int)blockIdx.x >= *nTiles) return;
  const int e    = tileE[blockIdx.x];
  const int base = tileBase[blockIdx.x];
  const int cnt  = tileCnt[blockIdx.x];
  const int ncol0 = blockIdx.y * BN;

  __shared__ __align__(16) unsigned short As [BM*BK];
  __shared__ __align__(16) unsigned short Bus[BN*BK];
  __shared__ __align__(16) unsigned short Bvs[BN*BK];

  const int tid  = threadIdx.x;
  const int srow = tid >> 1;
  const int sseg = tid & 1;

  const int arow = (srow < cnt) ? srow : 0;
  const int tokA = perm[base + arow];
  const unsigned short* aSrc = xb + (size_t)tokA * DMODEL + sseg*32;
  int brow = ncol0 + srow; if (brow >= HID) brow = HID - 1;
  const float* buSrc = Wu + ((size_t)e*HID + brow)*DMODEL + sseg*32;
  const float* bvSrc = Wv + ((size_t)e*HID + brow)*DMODEL + sseg*32;

  char* aBase  = (char*)As  + srow*128;
  char* buBase = (char*)Bus + srow*128;
  char* bvBase = (char*)Bvs + srow*128;
  const int swz = (srow & 7) << 4;

  const int wid = tid >> 6, lane = tid & 63;
  const int wm = (wid >> 1) * 64, wn = (wid & 1) * 64;
  const int fr = lane & 15, fq = lane >> 4;

  f32x4 accU[4][4], accV[4][4];
  #pragma unroll
  for (int m = 0; m < 4; m++)
    #pragma unroll
    for (int n = 0; n < 4; n++)
      #pragma unroll
      for (int j = 0; j < 4; j++){ accU[m][n][j] = 0.f; accV[m][n][j] = 0.f; }

  for (int kb = 0; kb < DMODEL; kb += BK){
    #pragma unroll
    for (int c = 0; c < 4; c++){
      u16x8 av = *(const u16x8*)(aSrc + kb + c*8);
      *(u16x8*)(aBase + ((sseg*64 + c*16) ^ swz)) = av;
    }
    #pragma unroll
    for (int c = 0; c < 4; c++){
      float4 f0 = *(const float4*)(buSrc + kb + c*8);
      float4 f1 = *(const float4*)(buSrc + kb + c*8 + 4);
      u16x8 o;
      o[0]=f2bf(f0.x); o[1]=f2bf(f0.y); o[2]=f2bf(f0.z); o[3]=f2bf(f0.w);
      o[4]=f2bf(f1.x); o[5]=f2bf(f1.y); o[6]=f2bf(f1.z); o[7]=f2bf(f1.w);
      *(u16x8*)(buBase + ((sseg*64 + c*16) ^ swz)) = o;
    }
    #pragma unroll
    for (int c = 0; c < 4; c++){
      float4 f0 = *(const float4*)(bvSrc + kb + c*8);
      float4 f1 = *(const float4*)(bvSrc + kb + c*8 + 4);
      u16x8 o;
      o[0]=f2bf(f0.x); o[1]=f2bf(f0.y); o[2]=f2bf(f0.z); o[3]=f2bf(f0.w);
      o[4]=f2bf(f1.x); o[5]=f2bf(f1.y); o[6]=f2bf(f1.z); o[7]=f2bf(f1.w);
      *(u16x8*)(bvBase + ((sseg*64 + c*16) ^ swz)) = o;
    }
    __syncthreads();
    #pragma unroll
    for (int ks = 0; ks < 2; ks++){
      bf16x8 af[4], bu[4], bv[4];
      #pragma unroll
      for (int m = 0; m < 4; m++){
        int r = wm + m*16 + fr;
        af[m] = *(const bf16x8*)((const char*)As + r*128 + ((ks*64 + fq*16) ^ ((r&7)<<4)));
      }
      #pragma unroll
      for (int n = 0; n < 4; n++){
        int r = wn + n*16 + fr;
        bu[n] = *(const bf16x8*)((const char*)Bus + r*128 + ((ks*64 + fq*16) ^ ((r&7)<<4)));
        bv[n] = *(const bf16x8*)((const char*)Bvs + r*128 + ((ks*64 + fq*16) ^ ((r&7)<<4)));
      }
      #pragma unroll
      for (int m = 0; m < 4; m++)
        #pragma unroll
        for (int n = 0; n < 4; n++){
          accU[m][n] = __builtin_amdgcn_mfma_f32_16x16x32_bf16(af[m], bu[n], accU[m][n], 0,0,0);
          accV[m][n] = __builtin_amdgcn_mfma_f32_16x16x32_bf16(af[m], bv[n], accV[m][n], 0,0,0);
        }
    }
    __syncthreads();
  }
  #pragma unroll
  for (int m = 0; m < 4; m++)
    #pragma unroll
    for (int n = 0; n < 4; n++)
      #pragma unroll
      for (int j = 0; j < 4; j++){
        int r = wm + m*16 + fq*4 + j;
        int c = ncol0 + wn + n*16 + fr;
        if (r < cnt && c < HID){
          float u = accU[m][n][j], v = accV[m][n][j];
          float hv = (u / (1.f + __expf(-u))) * v;
          h[(size_t)(base + r)*HID + c] = f2bf(hv);
        }
      }
}

__global__ __launch_bounds__(256,2) void k_downf(
    const unsigned short* __restrict__ h, const float* __restrict__ Wd,
    const int* __restrict__ perm, const float* __restrict__ gate,
    const int* __restrict__ nTiles, const int* __restrict__ tileE,
    const int* __restrict__ tileBase, const int* __restrict__ tileCnt,
    float* __restrict__ out)
{
  if ((int)blockIdx.x >= *nTiles) return;
  const int e    = tileE[blockIdx.x];
  const int base = tileBase[blockIdx.x];
  const int cnt  = tileCnt[blockIdx.x];
  const int ncol0 = blockIdx.y * BN;

  __shared__ __align__(16) unsigned short As[BM*BK];
  __shared__ __align__(16) unsigned short Bs[BM*BK];
  __shared__ int   tokL[BM];
  __shared__ float gateL[BM];

  const int tid = threadIdx.x;
  if (tid < BM){
    int rr = (tid < cnt) ? tid : 0;
    int tk = perm[base + rr];
    tokL[tid] = tk;
    gateL[tid] = gate[tk];
  }
  const int srow = tid >> 1;
  const int sseg = tid & 1;
  const int aslot = base + ((srow < cnt) ? srow : 0);
  const unsigned short* aSrc = h + (size_t)aslot*HID + sseg*32;
  const float* bSrc = Wd + ((size_t)e*DMODEL + ncol0 + srow)*HID + sseg*32;

  char* aBase = (char*)As + srow*128;
  char* bBase = (char*)Bs + srow*128;
  const int swz = (srow & 7) << 4;

  const int wid = tid >> 6, lane = tid & 63;
  const int wm = (wid >> 1) * 64, wn = (wid & 1) * 64;
  const int fr = lane & 15, fq = lane >> 4;

  f32x4 acc[4][4];
  #pragma unroll
  for (int m = 0; m < 4; m++)
    #pragma unroll
    for (int n = 0; n < 4; n++)
      #pragma unroll
      for (int j = 0; j < 4; j++) acc[m][n][j] = 0.f;

  for (int kb = 0; kb < HID; kb += BK){
    #pragma unroll
    for (int c = 0; c < 4; c++){
      u16x8 av = *(const u16x8*)(aSrc + kb + c*8);
      *(u16x8*)(aBase + ((sseg*64 + c*16) ^ swz)) = av;
    }
    #pragma unroll
    for (int c = 0; c < 4; c++){
      float4 f0 = *(const float4*)(bSrc + kb + c*8);
      float4 f1 = *(const float4*)(bSrc + kb + c*8 + 4);
      u16x8 o;
      o[0]=f2bf(f0.x); o[1]=f2bf(f0.y); o[2]=f2bf(f0.z); o[3]=f2bf(f0.w);
      o[4]=f2bf(f1.x); o[5]=f2bf(f1.y); o[6]=f2bf(f1.z); o[7]=f2bf(f1.w);
      *(u16x8*)(bBase + ((sseg*64 + c*16) ^ swz)) = o;
    }
    __syncthreads();
    #pragma unroll
    for (int ks = 0; ks < 2; ks++){
      bf16x8 af[4], bf[4];
      #pragma unroll
      for (int m = 0; m < 4; m++){
        int r = wm + m*16 + fr;
        af[m] = *(const bf16x8*)((const char*)As + r*128 + ((ks*64 + fq*16) ^ ((r&7)<<4)));
      }
      #pragma unroll
      for (int n = 0; n < 4; n++){
        int r = wn + n*16 + fr;
        bf[n] = *(const bf16x8*)((const char*)Bs + r*128 + ((ks*64 + fq*16) ^ ((r&7)<<4)));
      }
      #pragma unroll
      for (int m = 0; m < 4; m++)
        #pragma unroll
        for (int n = 0; n < 4; n++)
          acc[m][n] = __builtin_amdgcn_mfma_f32_16x16x32_bf16(af[m], bf[n], acc[m][n], 0,0,0);
    }
    __syncthreads();
  }
  #pragma unroll
  for (int m = 0; m < 4; m++)
    #pragma unroll
    for (int n = 0; n < 4; n++)
      #pragma unroll
      for (int j = 0; j < 4; j++){
        int r = wm + m*16 + fq*4 + j;
        int c = ncol0 + wn + n*16 + fr;
        if (r < cnt)
          out[(size_t)tokL[r]*DMODEL + c] = acc[m][n][j] * gateL[r];
      }
}

// ---------------- launch ----------------
extern "C" void kernel_launch(void* const* d_in, const int* in_sizes, int n_in,
                              void* d_out, int out_size, void* d_ws, size_t ws_size,
                              hipStream_t stream)
{
  const float* x  = (const float*)d_in[0];
  const float* Wg = (const float*)d_in[1];
  const float* bg = (const float*)d_in[2];
  const float* Wu = (const float*)d_in[3];
  const float* Wv = (const float*)d_in[4];
  const float* Wd = (const float*)d_in[5];
  float* out = (float*)d_out;

  char* ws = (char*)d_ws;
  int*   counts   = (int*)(ws + 0);
  int*   cursor   = (int*)(ws + 32);
  int*   offsets  = (int*)(ws + 64);
  float* ce_sum   = (float*)(ws + 128);
  int*   nTiles   = (int*)(ws + 192);
  int*   tileE    = (int*)(ws + 256);
  int*   tileBase = (int*)(ws + 768);
  int*   tileCnt  = (int*)(ws + 1280);
  int*   top1     = (int*)(ws + 2048);
  float* gate     = (float*)(ws + 34816);
  int*   perm     = (int*)(ws + 67584);
  unsigned short* xb   = (unsigned short*)(ws + 100352);
  unsigned short* hbuf = (unsigned short*)(ws + 100352 + (size_t)NTOK*DMODEL*2);   // +16,777,216
  const size_t W_ELEMS = (size_t)NEXP*HID*DMODEL;           // 22,544,384
  const size_t baseW = 100352 + (size_t)NTOK*DMODEL*2 + (size_t)NTOK*HID*2;        // ~61.97 MB
  unsigned short* Wub = (unsigned short*)(ws + baseW);
  unsigned short* Wvb = (unsigned short*)(ws + baseW + W_ELEMS*2);
  unsigned short* Wdb = (unsigned short*)(ws + baseW + W_ELEMS*4);
  const size_t NEED = baseW + W_ELEMS*6;                     // ~197.2 MB

  k_init<<<1, 64, 0, stream>>>(counts, cursor, ce_sum);
  k_router<<<NTOK/16, 1024, 0, stream>>>(x, Wg, bg, counts, ce_sum, top1, gate);
  k_cvtn<<<2048, 256, 0, stream>>>(x, xb, NTOK*DMODEL/8);
  k_scan<<<1, 64, 0, stream>>>(counts, ce_sum, offsets, nTiles, tileE, tileBase, tileCnt,
                               out + (size_t)NTOK*DMODEL);
  k_scatter<<<NTOK/256, 256, 0, stream>>>(top1, cursor, offsets, perm);

  dim3 gUp(MAXTILES, (HID + BN - 1)/BN);   // 72 x 22
  dim3 gDn(MAXTILES, DMODEL/BN);           // 72 x 8

  if (ws_size >= NEED){
    const int w8 = (int)(W_ELEMS/8);
    k_cvtn<<<2048, 256, 0, stream>>>(Wu, Wub, w8);
    k_cvtn<<<2048, 256, 0, stream>>>(Wv, Wvb, w8);
    k_cvtn<<<2048, 256, 0, stream>>>(Wd, Wdb, w8);
    k_up16<<<gUp, 256, 0, stream>>>(xb, Wub, Wvb, perm, nTiles, tileE, tileBase, tileCnt, hbuf);
    k_down16<<<gDn, 256, 0, stream>>>(hbuf, Wdb, perm, gate, nTiles, tileE, tileBase, tileCnt, out);
  } else {
    k_upf<<<gUp, 256, 0, stream>>>(xb, Wu, Wv, perm, nTiles, tileE, tileBase, tileCnt, hbuf);
    k_downf<<<gDn, 256, 0, stream>>>(hbuf, Wd, perm, gate, nTiles, tileE, tileBase, tileCnt, out);
  }
}